// Round 3
// baseline (28055.081 us; speedup 1.0000x reference)
//
#include <hip/hip_runtime.h>
#include <stdint.h>

// ---------------------------------------------------------------------------
// Bidirectional 2-layer LSTM. Two-phase per layer:
//  Phase A (parallel): xg = x . W_ih^T + b  (bf16 MFMA GEMM), layout [t][U][m][g]
//  Phase B (scan): persistent waves, W_hh resident in VGPRs (128 regs).
//    Cross-wave h broadcast is a TAGGED 8-byte atomic: {u32 step-tag, 2xbf16}.
//    Consumers poll the data itself (tag==s) -> signal+data in ONE coherence RT.
//    No flags, no fences, no vmcnt drains on the critical path.
// Per scan: 8 WGs x 4 waves; wave owns 16 units x 4 gates x 16 batch rows.
// Sync groups decouple into (scan, batch-half): 16-wave all-to-all.
// MFMA 16x16x32 bf16:  A: lane=(m=lane&15, k=quad*8+j)  B: (k=quad*8+j, n=lane&15)
//                      C/D: (row=quad*4+reg, col=lane&15)
// ---------------------------------------------------------------------------

#define Bn 32
#define Tn 2048
#define Hn 256

typedef short short8 __attribute__((ext_vector_type(8)));
typedef float f32x4 __attribute__((ext_vector_type(4)));

__device__ inline unsigned short f2b(float f) {  // fp32 -> bf16 RNE
  union { float f; unsigned u; } v; v.f = f;
  unsigned r = v.u + 0x7fffu + ((v.u >> 16) & 1u);
  return (unsigned short)(r >> 16);
}
__device__ inline float b2f(unsigned short b) {
  union { unsigned u; float f; } v; v.u = ((unsigned)b) << 16;
  return v.f;
}
__device__ inline float sigx(float x) {
  return __builtin_amdgcn_rcpf(1.f + __expf(-x));
}
__device__ inline float tanhx(float x) {
  return 2.f * __builtin_amdgcn_rcpf(1.f + __expf(-2.f * x)) - 1.f;
}

// ---------------- Phase A: xg = A . W^T + b  ------------------------------
// A: [B*T, K] (fp32 x if AF32 else bf16 h0out). Output xg bf16, per scan
// laid out as [t][u(0..255)][m(0..31)][g(0..3)] so the scan's per-lane 16
// values are one contiguous 32B chunk.
template <int K, bool AF32>
__global__ __launch_bounds__(256, 2) void xg_gemm(
    const void* __restrict__ Ain,
    const float* __restrict__ Wf, const float* __restrict__ bf_,
    const float* __restrict__ Wr, const float* __restrict__ br_,
    unsigned short* __restrict__ xg) {
  constexpr int KI = K / 32;
  const int bid = blockIdx.x;
  const int scan = bid & 1;
  const int sgrp = (bid >> 1) & 7;
  const int mchunk = bid >> 4;           // 0..255
  const int wave = threadIdx.x >> 6;
  const int lane = threadIdx.x & 63;
  const int l15 = lane & 15, quad = lane >> 4;
  const int stripe = sgrp * 4 + wave;    // 0..31 -> 32 gate-cols each
  const int gi0 = stripe * 32;

  const float* W = scan ? Wr : Wf;
  const float* bias = scan ? br_ : bf_;

  short8 bfr[KI][2];
  float bias2[2];
#pragma unroll
  for (int sub = 0; sub < 2; ++sub) {
    const int gi = gi0 + sub * 16 + l15;
    bias2[sub] = bias[gi];
#pragma unroll
    for (int ki = 0; ki < KI; ++ki) {
      const float* src = W + (size_t)gi * K + ki * 32 + quad * 8;
      short8 v;
#pragma unroll
      for (int j = 0; j < 8; ++j) v[j] = (short)f2b(src[j]);
      bfr[ki][sub] = v;
    }
  }

  const size_t scan_off = (size_t)scan << 26;  // elements per scan
#pragma unroll 1
  for (int mt0 = 0; mt0 < 16; ++mt0) {
    const int mt = mchunk * 16 + mt0;
    const size_t row = (size_t)mt * 16 + l15;
    f32x4 acc[2];
#pragma unroll
    for (int sub = 0; sub < 2; ++sub) {
      f32x4 bi = {bias2[sub], bias2[sub], bias2[sub], bias2[sub]};
      acc[sub] = bi;
    }
#pragma unroll
    for (int ki = 0; ki < KI; ++ki) {
      short8 af;
      if constexpr (AF32) {
        const float* ap = (const float*)Ain + row * K + ki * 32 + quad * 8;
        f32x4 a0 = *(const f32x4*)ap;
        f32x4 a1 = *(const f32x4*)(ap + 4);
#pragma unroll
        for (int j = 0; j < 4; ++j) { af[j] = (short)f2b(a0[j]); af[4 + j] = (short)f2b(a1[j]); }
      } else {
        const unsigned short* ap = (const unsigned short*)Ain + row * K + ki * 32 + quad * 8;
        af = *(const short8*)ap;
      }
#pragma unroll
      for (int sub = 0; sub < 2; ++sub)
        acc[sub] = __builtin_amdgcn_mfma_f32_16x16x32_bf16(af, bfr[ki][sub], acc[sub], 0, 0, 0);
    }
#pragma unroll
    for (int sub = 0; sub < 2; ++sub) {
      const int gi = gi0 + sub * 16 + l15;
      const int g = gi >> 8, u = gi & 255;
#pragma unroll
      for (int r = 0; r < 4; ++r) {
        const int orow = mt * 16 + quad * 4 + r;
        const int m = orow >> 11, t = orow & 2047;
        xg[scan_off + (((size_t)t * 256 + u) * 32 + m) * 4 + g] = f2b(acc[sub][r]);
      }
    }
  }
}

// ---------------- Phase B: recurrent scan ---------------------------------
// hq: [2 scans][2 parity][32 m][128 pairs] u64 = {tag, 2xbf16}
template <bool LAYER1>
__global__ __launch_bounds__(256, 1) void lstm_scan(
    const unsigned short* __restrict__ xg,
    const float* __restrict__ Whh_f, const float* __restrict__ Whh_r,
    unsigned long long* __restrict__ hq,
    unsigned short* __restrict__ h0out,      // [B][T][512] bf16 (layer0)
    float* __restrict__ dout) {              // [B][T][512] f32  (layer1)
  const int bid = blockIdx.x;
  const int scan = bid & 1;
  const int wg = bid >> 1;                   // 0..7
  const int wave = threadIdx.x >> 6;
  const int lane = threadIdx.x & 63;
  const int slot = wg * 4 + wave;            // 0..31
  const int cg = slot >> 1, mh = slot & 1;
  const int l15 = lane & 15, quad = lane >> 4;
  const int U = cg * 16 + l15;               // owned hidden unit
  const int mrow = mh * 16 + l15;            // A-frag batch row

  const float* Whh = scan ? Whh_r : Whh_f;

  // resident W_hh B-fragments: 8 ki x 4 gates x 4 VGPR = 128 VGPRs
  short8 bfh[8][4];
#pragma unroll
  for (int ki = 0; ki < 8; ++ki) {
#pragma unroll
    for (int g = 0; g < 4; ++g) {
      const float* src = Whh + (size_t)(g * Hn + U) * Hn + ki * 32 + quad * 8;
      short8 v;
#pragma unroll
      for (int j = 0; j < 8; ++j) v[j] = (short)f2b(src[j]);
      bfh[ki][g] = v;
    }
  }

  unsigned long long* myq = hq + (size_t)scan * 8192;
  const size_t scan_off = (size_t)scan << 26;

  float c_st[4] = {0.f, 0.f, 0.f, 0.f};

  for (int s = 0; s < Tn; ++s) {
    const int t = scan ? (Tn - 1 - s) : s;

    // xg preactivations: one contiguous 32B read, issued before the poll so
    // its HBM latency hides under the wait.
    const unsigned short* xgp =
        xg + scan_off + (((size_t)t * 256 + U) * 32 + mh * 16 + quad * 4) * 4;
    short8 x0 = *(const short8*)xgp;
    short8 x1 = *(const short8*)(xgp + 8);

    // tagged h_{s-1}: poll the data itself (tag == s). 32 pipelined u64 loads
    // per attempt -> signal + data in one coherence round-trip.
    unsigned long long q[8][4];
    if (s > 0) {
      const unsigned long long* src =
          myq + (size_t)((s - 1) & 1) * 4096 + (size_t)mrow * 128;
      bool ok;
      do {
#pragma unroll
        for (int ki = 0; ki < 8; ++ki)
#pragma unroll
          for (int n = 0; n < 4; ++n)
            q[ki][n] = __hip_atomic_load(src + ki * 16 + quad * 4 + n,
                                         __ATOMIC_RELAXED, __HIP_MEMORY_SCOPE_AGENT);
        ok = true;
#pragma unroll
        for (int ki = 0; ki < 8; ++ki)
#pragma unroll
          for (int n = 0; n < 4; ++n)
            ok &= ((unsigned)(q[ki][n] >> 32) == (unsigned)s);
      } while (!__all(ok));
    }

    f32x4 acc[4];
#pragma unroll
    for (int g = 0; g < 4; ++g) {
      f32x4 a = {b2f((unsigned short)x0[g]), b2f((unsigned short)x0[4 + g]),
                 b2f((unsigned short)x1[g]), b2f((unsigned short)x1[4 + g])};
      acc[g] = a;
    }

    if (s > 0) {
#pragma unroll
      for (int ki = 0; ki < 8; ++ki) {
        union { unsigned u[4]; short8 s8; } uu;
#pragma unroll
        for (int n = 0; n < 4; ++n) uu.u[n] = (unsigned)q[ki][n];
#pragma unroll
        for (int g = 0; g < 4; ++g)
          acc[g] = __builtin_amdgcn_mfma_f32_16x16x32_bf16(uu.s8, bfh[ki][g], acc[g], 0, 0, 0);
      }
    }

    // gates + state; tagged broadcast stores fire ASAP (per row)
    float hvals[4];
    unsigned long long* dst = myq + (size_t)(s & 1) * 4096;
#pragma unroll
    for (int r = 0; r < 4; ++r) {
      const int m = mh * 16 + quad * 4 + r;
      float ig = sigx(acc[0][r]), fg = sigx(acc[1][r]);
      float gg = tanhx(acc[2][r]), og = sigx(acc[3][r]);
      float cv = fg * c_st[r] + ig * gg;
      c_st[r] = cv;
      float hv = og * tanhx(cv);
      hvals[r] = hv;
      unsigned short hb16 = f2b(hv);
      unsigned pk = ((unsigned)__shfl_xor((int)hb16, 1)) & 0xffffu;
      if (!(lane & 1)) {
        unsigned pair = (unsigned)hb16 | (pk << 16);
        unsigned long long v = (((unsigned long long)(unsigned)(s + 1)) << 32) | pair;
        __hip_atomic_store(dst + m * 128 + (U >> 1), v,
                           __ATOMIC_RELAXED, __HIP_MEMORY_SCOPE_AGENT);
      }
    }

    // plain output stores: off the critical path, nothing ever waits on them
#pragma unroll
    for (int r = 0; r < 4; ++r) {
      const int m = mh * 16 + quad * 4 + r;
      if constexpr (!LAYER1)
        h0out[((size_t)m * Tn + t) * 512 + scan * Hn + U] = f2b(hvals[r]);
      else
        dout[((size_t)m * Tn + t) * 512 + scan * Hn + U] = hvals[r];
    }
  }
}

extern "C" void kernel_launch(void* const* d_in, const int* in_sizes, int n_in,
                              void* d_out, int out_size, void* d_ws, size_t ws_size,
                              hipStream_t stream) {
  (void)in_sizes; (void)n_in; (void)out_size; (void)ws_size;
  const float* x      = (const float*)d_in[0];
  const float* Wih_f0 = (const float*)d_in[1];
  const float* Whh_f0 = (const float*)d_in[2];
  const float* b_f0   = (const float*)d_in[3];
  const float* Wih_r0 = (const float*)d_in[4];
  const float* Whh_r0 = (const float*)d_in[5];
  const float* b_r0   = (const float*)d_in[6];
  const float* Wih_f1 = (const float*)d_in[7];
  const float* Whh_f1 = (const float*)d_in[8];
  const float* b_f1   = (const float*)d_in[9];
  const float* Wih_r1 = (const float*)d_in[10];
  const float* Whh_r1 = (const float*)d_in[11];
  const float* b_r1   = (const float*)d_in[12];

  char* ws = (char*)d_ws;
  unsigned short* xgbuf = (unsigned short*)ws;                 // 268,435,456 B
  size_t off = (size_t)2 * Tn * Bn * 1024 * sizeof(unsigned short);
  unsigned short* h0out = (unsigned short*)(ws + off);         // 67,108,864 B
  off += (size_t)Bn * Tn * 512 * sizeof(unsigned short);
  unsigned long long* hqA = (unsigned long long*)(ws + off); off += 2 * 8192 * 8;
  unsigned long long* hqB = (unsigned long long*)(ws + off); off += 2 * 8192 * 8;
  // No init needed: 0xAA poison (or zeros) never equals a valid tag 1..2048.

  dim3 blk(256);
  // layer 0
  xg_gemm<256, true><<<dim3(4096), blk, 0, stream>>>(
      (const void*)x, Wih_f0, b_f0, Wih_r0, b_r0, xgbuf);
  lstm_scan<false><<<dim3(16), blk, 0, stream>>>(
      xgbuf, Whh_f0, Whh_r0, hqA, h0out, (float*)nullptr);
  // layer 1
  xg_gemm<512, false><<<dim3(4096), blk, 0, stream>>>(
      (const void*)h0out, Wih_f1, b_f1, Wih_r1, b_r1, xgbuf);
  lstm_scan<true><<<dim3(16), blk, 0, stream>>>(
      xgbuf, Whh_f1, Whh_r1, hqB, (unsigned short*)nullptr, (float*)d_out);
}